// Round 1
// baseline (3821.108 us; speedup 1.0000x reference)
//
#include <hip/hip_runtime.h>
#include <math.h>

#define Bz 64
#define Sz 200
#define Dz 128
#define NQz 50000
#define NCz 1000
#define MCz 4
#define Kz 10
#define Tz 199            // S-1 scan steps
#define NSz (Bz*Tz)       // 12736 (b,t) slots; 12736/64 = 199 exactly
#define NEz (NQz*MCz)     // 200000 edges

// ---------------- GNN: CSR build + per-concept aggregation ----------------
__global__ void k_count(const int* __restrict__ qt, int* __restrict__ cnt) {
    int e = blockIdx.x*256 + threadIdx.x;
    if (e < NEz) atomicAdd(&cnt[qt[e]], 1);
}

__global__ void k_offs(const int* __restrict__ cnt, int* __restrict__ offs) {
    __shared__ int s[1024];
    int tid = threadIdx.x;
    s[tid] = (tid < NCz) ? cnt[tid] : 0;
    __syncthreads();
    for (int off = 1; off < 1024; off <<= 1) {
        int add = (tid >= off) ? s[tid - off] : 0;
        __syncthreads();
        s[tid] += add;
        __syncthreads();
    }
    if (tid < NCz) offs[tid + 1] = s[tid];
    if (tid == 0) offs[0] = 0;
}

__global__ void k_fill(const int* __restrict__ qt, const int* __restrict__ offs,
                       int* __restrict__ fill, int* __restrict__ edge_q) {
    int e = blockIdx.x*256 + threadIdx.x;
    if (e < NEz) {
        int c = qt[e];
        int pos = atomicAdd(&fill[c], 1);
        edge_q[offs[c] + pos] = e >> 2;     // question id
    }
}

// m2[c] = mean over edges (q->c) of ( emb_q[q] + 0.25*sum_m emb_c[q_table[q][m]] )
__global__ void k_m2(const int* __restrict__ qt, const int* __restrict__ offs,
                     const int* __restrict__ edge_q,
                     const float* __restrict__ emb_q, const float* __restrict__ emb_c,
                     float* __restrict__ m2) {
    int c = blockIdx.x;
    int g = threadIdx.x >> 7;      // 0..3
    int d = threadIdx.x & 127;
    int e0 = offs[c], e1 = offs[c+1];
    float acc = 0.f;
    for (int e = e0 + g; e < e1; e += 4) {
        int q = edge_q[e];
        const int* t4 = qt + q*4;
        int c0 = t4[0], c1 = t4[1], c2 = t4[2], c3 = t4[3];
        acc += emb_q[q*128 + d]
             + 0.25f*(emb_c[c0*128+d] + emb_c[c1*128+d] + emb_c[c2*128+d] + emb_c[c3*128+d]);
    }
    __shared__ float ps[4][128];
    ps[g][d] = acc;
    __syncthreads();
    if (g == 0) {
        float tot = ps[0][d] + ps[1][d] + ps[2][d] + ps[3][d];
        float cn = (float)(e1 - e0);
        m2[c*128 + d] = tot / fmaxf(cn, 1.0f);
    }
}

// ---------------- small 128x128 matmuls (weight folding) ----------------
template<bool TR>
__global__ void k_mm128(const float* __restrict__ X, const float* __restrict__ Y,
                        float* __restrict__ out) {
    int r = blockIdx.x, c = threadIdx.x;
    float acc = 0.f;
    for (int e = 0; e < 128; ++e) acc += X[r*128 + e] * Y[e*128 + c];
    if (TR) out[c*128 + r] = acc;           // store transposed (Mt[d][r] = M[r][d])
    else    out[r*128 + c] = acc;
}

// gr[rt][r] = bih1[r] + sum_e emb_r[rt][e]*Wih1[r][128+e]   (response-part of gi1, bias folded)
__global__ void k_gr(const float* __restrict__ emb_r, const float* __restrict__ Wih1,
                     const float* __restrict__ bih1, float* __restrict__ gr) {
    int rt = threadIdx.x / 384, r = threadIdx.x % 384;   // block 768
    float acc = bih1[r];
    for (int e = 0; e < 128; ++e) acc += emb_r[rt*128 + e] * Wih1[r*256 + 128 + e];
    gr[rt*384 + r] = acc;
}

// Bkq rows 0..127: G = Wq^T Wk;  row 128: wkb = Wk^T bq;  row 129: Ww[0][128:256]
// biaskq: 0..127: Wq^T bk;  128: bq.bk;  129: bw
__global__ void k_bkq(const float* __restrict__ Wq, const float* __restrict__ Wk,
                      const float* __restrict__ bq, const float* __restrict__ bk,
                      const float* __restrict__ Ww, const float* __restrict__ bw,
                      float* __restrict__ Bkq, float* __restrict__ biaskq) {
    int r = blockIdx.x, d = threadIdx.x;
    if (r < 128) {
        float acc = 0.f;
        for (int n = 0; n < 128; ++n) acc += Wq[n*128 + r] * Wk[n*128 + d];
        Bkq[r*128 + d] = acc;
        if (d == 0) {
            float b0 = 0.f;
            for (int n = 0; n < 128; ++n) b0 += Wq[n*128 + r] * bk[n];
            biaskq[r] = b0;
        }
    } else if (r == 128) {
        float acc = 0.f;
        for (int n = 0; n < 128; ++n) acc += bq[n] * Wk[n*128 + d];
        Bkq[128*128 + d] = acc;
        if (d == 0) {
            float c0 = 0.f;
            for (int n = 0; n < 128; ++n) c0 += bq[n] * bk[n];
            biaskq[128] = c0;
        }
    } else {
        Bkq[129*128 + d] = Ww[128 + d];
        if (d == 0) biaskq[129] = bw[0];
    }
}

// ---------------- per-slot GNN question embedding ----------------
// e_q[slot] = mask ? tanh(u @ M^T + bagg) : emb_q[q],  u = emb_q + 0.5*sum(emb_c) + 0.25*sum(m2)
__global__ void k_eq(const float* __restrict__ Mt_g, const float* __restrict__ bagg,
                     const float* __restrict__ emb_q, const float* __restrict__ emb_c,
                     const float* __restrict__ m2, const int* __restrict__ qseq,
                     const int* __restrict__ mseq, const int* __restrict__ qt,
                     float* __restrict__ eq) {
    __shared__ float Mt[128*128];
    __shared__ float ub[2][128];
    int tid = threadIdx.x;
    for (int i = tid; i < 128*128/4; i += 256)
        ((float4*)Mt)[i] = ((const float4*)Mt_g)[i];
    __syncthreads();
    int g = tid >> 7, d = tid & 127;
    for (int it = 0; it < 8; ++it) {
        int slot = blockIdx.x*16 + it*2 + g;            // grid 796 -> slots exactly cover NSz
        int b = slot / Tz, t = slot % Tz;
        int q = qseq[b*Sz + t];
        int msk = mseq[b*Sz + t];
        if (msk) {
            const int* t4 = qt + q*4;
            int c0 = t4[0], c1 = t4[1], c2 = t4[2], c3 = t4[3];
            ub[g][d] = emb_q[q*128 + d]
                     + 0.5f *(emb_c[c0*128+d] + emb_c[c1*128+d] + emb_c[c2*128+d] + emb_c[c3*128+d])
                     + 0.25f*(m2[c0*128+d]  + m2[c1*128+d]  + m2[c2*128+d]  + m2[c3*128+d]);
        }
        __syncthreads();
        if (msk) {
            float acc = bagg[d];
            const float* urow = ub[g];
            for (int e = 0; e < 128; ++e) acc += Mt[e*128 + d] * urow[e];
            eq[slot*128 + d] = tanhf(acc);
        } else {
            eq[slot*128 + d] = emb_q[q*128 + d];
        }
        __syncthreads();
    }
}

// ---------------- generic tiled fp32 GEMM: C[s][n] = A[s][:128] . Bm[n][:128] + epilogue ----
// MODE 0: + bias[n]   (kq path)     MODE 1: + gr[rt(s)][n]  (gi1 path)
template<int MODE>
__global__ void k_gemm(const float* __restrict__ A, const float* __restrict__ Bm,
                       int ldb, int nB, float* __restrict__ C, int ldc,
                       const float* __restrict__ bias, const float* __restrict__ gr,
                       const int* __restrict__ cseq) {
    __shared__ float As[64][33];
    __shared__ float Bs[64][33];
    __shared__ int rtb[64];
    int tx = threadIdx.x, ty = threadIdx.y;
    int tid = ty*16 + tx;
    int m0 = blockIdx.x * 64;
    int n0 = blockIdx.y * 64;
    if (MODE == 1 && tid < 64) {
        int s = m0 + tid;
        int b = s / Tz, t = s % Tz;
        rtb[tid] = cseq[b*Sz + t];
    }
    float acc[4][4];
    #pragma unroll
    for (int i = 0; i < 4; ++i)
        #pragma unroll
        for (int j = 0; j < 4; ++j) acc[i][j] = 0.f;

    for (int kc = 0; kc < 128; kc += 32) {
        #pragma unroll
        for (int l = 0; l < 2; ++l) {
            int v = tid*2 + l;                 // 0..511
            int row = v >> 3, c4 = (v & 7) << 2;
            float4 av = *(const float4*)(A + (size_t)(m0+row)*128 + kc + c4);
            As[row][c4+0] = av.x; As[row][c4+1] = av.y; As[row][c4+2] = av.z; As[row][c4+3] = av.w;
            int nrow = n0 + row;
            float4 bv = make_float4(0.f, 0.f, 0.f, 0.f);
            if (nrow < nB) bv = *(const float4*)(Bm + (size_t)nrow*ldb + kc + c4);
            Bs[row][c4+0] = bv.x; Bs[row][c4+1] = bv.y; Bs[row][c4+2] = bv.z; Bs[row][c4+3] = bv.w;
        }
        __syncthreads();
        #pragma unroll 8
        for (int k = 0; k < 32; ++k) {
            float av[4], bv[4];
            #pragma unroll
            for (int i = 0; i < 4; ++i) av[i] = As[ty*4+i][k];
            #pragma unroll
            for (int j = 0; j < 4; ++j) bv[j] = Bs[tx*4+j][k];
            #pragma unroll
            for (int i = 0; i < 4; ++i)
                #pragma unroll
                for (int j = 0; j < 4; ++j) acc[i][j] += av[i]*bv[j];
        }
        __syncthreads();
    }
    #pragma unroll
    for (int i = 0; i < 4; ++i) {
        int s = m0 + ty*4 + i;
        #pragma unroll
        for (int j = 0; j < 4; ++j) {
            int col = n0 + tx*4 + j;
            if (col < nB) {
                float v = acc[i][j];
                if (MODE == 0) v += bias[col];
                else           v += gr[rtb[ty*4+i]*384 + col];
                C[(size_t)s*ldc + col] = v;
            }
        }
    }
}

// ---------------- sequential GRU scan: one block per batch row ----------------
__global__ void k_scan(const float* __restrict__ gi1,
                       const float* __restrict__ Whh1, const float* __restrict__ bhh1,
                       const float* __restrict__ Wih2, const float* __restrict__ bih2,
                       const float* __restrict__ Whh2, const float* __restrict__ bhh2,
                       float* __restrict__ stateh) {
    __shared__ float h1[128], h2[128];
    __shared__ float gi[384], gh[384], gi2[384], gh2[384];
    int b = blockIdx.x, r = threadIdx.x;   // block 384 threads
    if (r < 128) { h1[r] = 0.f; h2[r] = 0.f; }
    __syncthreads();
    for (int t = 0; t < Tz; ++t) {
        int row = b*Tz + t;
        {   // phase 1: gh = Whh1 @ h1 + bhh1 ; gi from precomputed gi1
            float acc = bhh1[r];
            const float4* w  = (const float4*)(Whh1 + (size_t)r*128);
            const float4* hv = (const float4*)h1;
            #pragma unroll 8
            for (int k = 0; k < 32; ++k) {
                float4 wv = w[k]; float4 h4 = hv[k];
                acc += wv.x*h4.x + wv.y*h4.y + wv.z*h4.z + wv.w*h4.w;
            }
            gh[r] = acc;
            gi[r] = gi1[(size_t)row*384 + r];
        }
        __syncthreads();
        if (r < 128) {
            float rr = 1.f/(1.f + expf(-(gi[r]     + gh[r])));
            float zz = 1.f/(1.f + expf(-(gi[r+128] + gh[r+128])));
            float nn = tanhf(gi[r+256] + rr*gh[r+256]);
            h1[r] = (1.f - zz)*nn + zz*h1[r];
        }
        __syncthreads();
        {   // phase 2: gi2 = Wih2 @ h1' + bih2 ; gh2 = Whh2 @ h2 + bhh2
            float acc1 = bih2[r], acc2 = bhh2[r];
            const float4* w1  = (const float4*)(Wih2 + (size_t)r*128);
            const float4* w2  = (const float4*)(Whh2 + (size_t)r*128);
            const float4* h1v = (const float4*)h1;
            const float4* h2v = (const float4*)h2;
            #pragma unroll 4
            for (int k = 0; k < 32; ++k) {
                float4 a = w1[k], x1 = h1v[k];
                acc1 += a.x*x1.x + a.y*x1.y + a.z*x1.z + a.w*x1.w;
                float4 c = w2[k], x2 = h2v[k];
                acc2 += c.x*x2.x + c.y*x2.y + c.z*x2.z + c.w*x2.w;
            }
            gi2[r] = acc1; gh2[r] = acc2;
        }
        __syncthreads();
        if (r < 128) {
            float rr = 1.f/(1.f + expf(-(gi2[r]     + gh2[r])));
            float zz = 1.f/(1.f + expf(-(gi2[r+128] + gh2[r+128])));
            float nn = tanhf(gi2[r+256] + rr*gh2[r+256]);
            float hnew = (1.f - zz)*nn + zz*h2[r];
            h2[r] = hnew;
            stateh[(size_t)row*128 + r] = hnew;
        }
        __syncthreads();
    }
}

// ---------------- attention + top-k + output, one wave per (b,t) ----------------
__global__ void k_attn(const float* __restrict__ kqb, const int* __restrict__ qseq,
                       const int* __restrict__ qt, const float* __restrict__ emb_q,
                       const float* __restrict__ emb_c, const float* __restrict__ Ww,
                       float* __restrict__ out) {
    int t = blockIdx.x, b = blockIdx.y;
    int lane = threadIdx.x;           // block = 64 = 1 wave
    __shared__ float qc[5][128];
    __shared__ float gq[5];
    int qn = qseq[b*Sz + t + 1];
    for (int idx = lane; idx < 5*128; idx += 64) {
        int i = idx >> 7, d = idx & 127;
        const float* src = (i == 0) ? (emb_q + (size_t)qn*128)
                                    : (emb_c + (size_t)qt[qn*4 + (i-1)]*128);
        qc[i][d] = src[d];
    }
    __syncthreads();
    if (lane < 5) {
        float acc = 0.f;
        for (int d = 0; d < 128; ++d) acc += qc[lane][d]*Ww[d];
        gq[lane] = acc;
    }
    __syncthreads();

    const float NEG = -3.402823466e38f;
    float sv[10]; int si[10];
    #pragma unroll
    for (int k = 0; k < 10; ++k) { sv[k] = NEG; si[k] = 0x7FFFFFFF; }

    for (int j = lane; j <= t; j += 64) {
        const float* krow = kqb + (size_t)(b*Tz + j)*132;
        const float4* kr4 = (const float4*)krow;
        float a0=0.f, a1=0.f, a2=0.f, a3=0.f, a4=0.f;
        #pragma unroll 4
        for (int c = 0; c < 32; ++c) {
            float4 kv = kr4[c];
            float4 q0 = ((const float4*)qc[0])[c];
            float4 q1 = ((const float4*)qc[1])[c];
            float4 q2 = ((const float4*)qc[2])[c];
            float4 q3 = ((const float4*)qc[3])[c];
            float4 q4 = ((const float4*)qc[4])[c];
            a0 += q0.x*kv.x + q0.y*kv.y + q0.z*kv.z + q0.w*kv.w;
            a1 += q1.x*kv.x + q1.y*kv.y + q1.z*kv.z + q1.w*kv.w;
            a2 += q2.x*kv.x + q2.y*kv.y + q2.z*kv.z + q2.w*kv.w;
            a3 += q3.x*kv.x + q3.y*kv.y + q3.z*kv.z + q3.w*kv.w;
            a4 += q4.x*kv.x + q4.y*kv.y + q4.z*kv.z + q4.w*kv.w;
        }
        float kbj = krow[128];
        float scs[5] = {a0+kbj, a1+kbj, a2+kbj, a3+kbj, a4+kbj};
        #pragma unroll
        for (int i = 0; i < 5; ++i) {
            float cv = scs[i]; int ci = i*Sz + j;        // flat idx = i*S + j (ref order)
            #pragma unroll
            for (int k = 0; k < 10; ++k) {
                bool bet = (cv > sv[k]) || (cv == sv[k] && ci < si[k]);
                float tvv = sv[k]; int tii = si[k];
                if (bet) { sv[k] = cv; si[k] = ci; cv = tvv; ci = tii; }
            }
        }
    }

    // 10 rounds of global max (desc value, tie -> lower index), matching lax.top_k order
    float vmax = 0.f, myv = 0.f; int myidx = 0x7FFFFFFF;
    #pragma unroll
    for (int rnd = 0; rnd < 10; ++rnd) {
        float v = sv[0]; int idx = si[0];
        #pragma unroll
        for (int off = 32; off >= 1; off >>= 1) {
            float ov = __shfl_xor(v, off);
            int   oi = __shfl_xor(idx, off);
            if (ov > v || (ov == v && oi < idx)) { v = ov; idx = oi; }
        }
        if (rnd == 0) vmax = v;
        if (lane == rnd) { myv = v; myidx = idx; }
        if (si[0] == idx) {   // owner pops its head
            #pragma unroll
            for (int k = 0; k < 9; ++k) { sv[k] = sv[k+1]; si[k] = si[k+1]; }
            sv[9] = NEG; si[9] = 0x7FFFFFFF;
        }
    }

    float num = 0.f, den = 0.f;
    if (lane < 10 && myidx != 0x7FFFFFFF) {
        float a = expf(myv - vmax);
        int ik = myidx / Sz, jk = myidx % Sz;
        float gsj = kqb[(size_t)(b*Tz + jk)*132 + 129];       // Ww-state dot + bw
        float f = 1.f/(1.f + expf(-(gq[ik] + gsj)));
        num = a*f; den = a;
    }
    #pragma unroll
    for (int off = 32; off >= 1; off >>= 1) {
        num += __shfl_xor(num, off);
        den += __shfl_xor(den, off);
    }
    if (lane == 0) out[b*Sz + t + 1] = num/den;
}

// ---------------- host ----------------
static inline size_t alup(size_t x) { return (x + 255) & ~(size_t)255; }

extern "C" void kernel_launch(void* const* d_in, const int* in_sizes, int n_in,
                              void* d_out, int out_size, void* d_ws, size_t ws_size,
                              hipStream_t stream) {
    (void)in_sizes; (void)n_in; (void)ws_size;
    const float* emb_q = (const float*)d_in[0];
    const float* emb_c = (const float*)d_in[1];
    const float* emb_r = (const float*)d_in[2];
    const float* Wih1  = (const float*)d_in[3];
    const float* Whh1  = (const float*)d_in[4];
    const float* bih1  = (const float*)d_in[5];
    const float* bhh1  = (const float*)d_in[6];
    const float* Wih2  = (const float*)d_in[7];
    const float* Whh2  = (const float*)d_in[8];
    const float* bih2  = (const float*)d_in[9];
    const float* bhh2  = (const float*)d_in[10];
    const float* Wg1   = (const float*)d_in[11];
    const float* Wg2   = (const float*)d_in[12];
    const float* Wg3   = (const float*)d_in[13];
    const float* Wagg  = (const float*)d_in[14];
    const float* bagg  = (const float*)d_in[15];
    const float* Wq    = (const float*)d_in[16];
    const float* bq    = (const float*)d_in[17];
    const float* Wk    = (const float*)d_in[18];
    const float* bk    = (const float*)d_in[19];
    const float* Ww    = (const float*)d_in[20];
    const float* bw    = (const float*)d_in[21];
    const int* qseq    = (const int*)d_in[22];
    const int* cseq    = (const int*)d_in[23];
    const int* mseq    = (const int*)d_in[24];
    const int* qtab    = (const int*)d_in[25];
    float* out = (float*)d_out;

    char* p = (char*)d_ws;
    auto alloc = [&](size_t bytes) { char* r = p; p += alup(bytes); return r; };
    int*   cnt    = (int*)  alloc(4096);
    int*   fill   = (int*)  alloc(4096);               // contiguous with cnt
    int*   offs   = (int*)  alloc(1001*4);
    int*   edge_q = (int*)  alloc((size_t)NEz*4);
    float* m2     = (float*)alloc((size_t)NCz*128*4);
    float* T1     = (float*)alloc(128*128*4);
    float* T2     = (float*)alloc(128*128*4);
    float* Mt     = (float*)alloc(128*128*4);
    float* gr     = (float*)alloc(2*384*4);
    float* Bkq    = (float*)alloc(132*128*4);
    float* biaskq = (float*)alloc(132*4);
    float* eq     = (float*)alloc((size_t)NSz*128*4);
    float* gi1    = (float*)alloc((size_t)NSz*384*4);
    float* stateh = (float*)alloc((size_t)NSz*128*4);
    float* kqb    = (float*)alloc((size_t)NSz*132*4);

    hipMemsetAsync(cnt, 0, 8192, stream);                       // cnt + fill
    hipMemsetAsync(d_out, 0, (size_t)out_size*4, stream);       // y[:,0] = 0

    k_count<<<(NEz+255)/256, 256, 0, stream>>>(qtab, cnt);
    k_offs <<<1, 1024, 0, stream>>>(cnt, offs);
    k_fill <<<(NEz+255)/256, 256, 0, stream>>>(qtab, offs, fill, edge_q);
    k_m2   <<<NCz, 512, 0, stream>>>(qtab, offs, edge_q, emb_q, emb_c, m2);

    k_mm128<false><<<128, 128, 0, stream>>>(Wg2, Wg1, T1);      // T1 = Wg2*Wg1
    k_mm128<false><<<128, 128, 0, stream>>>(Wg3, T1, T2);       // T2 = Wg3*T1
    k_mm128<true> <<<128, 128, 0, stream>>>(Wagg, T2, Mt);      // Mt = (Wagg*T2)^T
    k_gr  <<<1, 768, 0, stream>>>(emb_r, Wih1, bih1, gr);
    k_bkq <<<130, 128, 0, stream>>>(Wq, Wk, bq, bk, Ww, bw, Bkq, biaskq);

    k_eq  <<<NSz/16, 256, 0, stream>>>(Mt, bagg, emb_q, emb_c, m2, qseq, mseq, qtab, eq);

    k_gemm<1><<<dim3(NSz/64, 6), dim3(16,16), 0, stream>>>(eq, Wih1, 256, 384,
                                                           gi1, 384, nullptr, gr, cseq);
    k_scan<<<Bz, 384, 0, stream>>>(gi1, Whh1, bhh1, Wih2, bih2, Whh2, bhh2, stateh);
    k_gemm<0><<<dim3(NSz/64, 3), dim3(16,16), 0, stream>>>(stateh, Bkq, 128, 132,
                                                           kqb, 132, biaskq, nullptr, nullptr);
    k_attn<<<dim3(Tz, Bz), 64, 0, stream>>>(kqb, qseq, qtab, emb_q, emb_c, Ww, out);
}

// Round 2
// 3183.028 us; speedup vs baseline: 1.2005x; 1.2005x over previous
//
#include <hip/hip_runtime.h>
#include <math.h>

#define Bz 64
#define Sz 200
#define Dz 128
#define NQz 50000
#define NCz 1000
#define MCz 4
#define Kz 10
#define Tz 199            // S-1 scan steps
#define NSz (Bz*Tz)       // 12736 (b,t) slots; 12736/64 = 199 exactly
#define NEz (NQz*MCz)     // 200000 edges

// ---------------- GNN: CSR build + per-concept aggregation ----------------
__global__ void k_count(const int* __restrict__ qt, int* __restrict__ cnt) {
    int e = blockIdx.x*256 + threadIdx.x;
    if (e < NEz) atomicAdd(&cnt[qt[e]], 1);
}

__global__ void k_offs(const int* __restrict__ cnt, int* __restrict__ offs) {
    __shared__ int s[1024];
    int tid = threadIdx.x;
    s[tid] = (tid < NCz) ? cnt[tid] : 0;
    __syncthreads();
    for (int off = 1; off < 1024; off <<= 1) {
        int add = (tid >= off) ? s[tid - off] : 0;
        __syncthreads();
        s[tid] += add;
        __syncthreads();
    }
    if (tid < NCz) offs[tid + 1] = s[tid];
    if (tid == 0) offs[0] = 0;
}

__global__ void k_fill(const int* __restrict__ qt, const int* __restrict__ offs,
                       int* __restrict__ fill, int* __restrict__ edge_q) {
    int e = blockIdx.x*256 + threadIdx.x;
    if (e < NEz) {
        int c = qt[e];
        int pos = atomicAdd(&fill[c], 1);
        edge_q[offs[c] + pos] = e >> 2;     // question id
    }
}

// m2[c] = mean over edges (q->c) of ( emb_q[q] + 0.25*sum_m emb_c[q_table[q][m]] )
__global__ void k_m2(const int* __restrict__ qt, const int* __restrict__ offs,
                     const int* __restrict__ edge_q,
                     const float* __restrict__ emb_q, const float* __restrict__ emb_c,
                     float* __restrict__ m2) {
    int c = blockIdx.x;
    int g = threadIdx.x >> 7;      // 0..3
    int d = threadIdx.x & 127;
    int e0 = offs[c], e1 = offs[c+1];
    float acc = 0.f;
    for (int e = e0 + g; e < e1; e += 4) {
        int q = edge_q[e];
        const int* t4 = qt + q*4;
        int c0 = t4[0], c1 = t4[1], c2 = t4[2], c3 = t4[3];
        acc += emb_q[q*128 + d]
             + 0.25f*(emb_c[c0*128+d] + emb_c[c1*128+d] + emb_c[c2*128+d] + emb_c[c3*128+d]);
    }
    __shared__ float ps[4][128];
    ps[g][d] = acc;
    __syncthreads();
    if (g == 0) {
        float tot = ps[0][d] + ps[1][d] + ps[2][d] + ps[3][d];
        float cn = (float)(e1 - e0);
        m2[c*128 + d] = tot / fmaxf(cn, 1.0f);
    }
}

// ---------------- small 128x128 matmuls (weight folding) ----------------
template<bool TR>
__global__ void k_mm128(const float* __restrict__ X, const float* __restrict__ Y,
                        float* __restrict__ out) {
    int r = blockIdx.x, c = threadIdx.x;
    float acc = 0.f;
    for (int e = 0; e < 128; ++e) acc += X[r*128 + e] * Y[e*128 + c];
    if (TR) out[c*128 + r] = acc;           // store transposed (Mt[d][r] = M[r][d])
    else    out[r*128 + c] = acc;
}

// gr[rt][r] = bih1[r] + sum_e emb_r[rt][e]*Wih1[r][128+e]   (response-part of gi1, bias folded)
__global__ void k_gr(const float* __restrict__ emb_r, const float* __restrict__ Wih1,
                     const float* __restrict__ bih1, float* __restrict__ gr) {
    int rt = threadIdx.x / 384, r = threadIdx.x % 384;   // block 768
    float acc = bih1[r];
    for (int e = 0; e < 128; ++e) acc += emb_r[rt*128 + e] * Wih1[r*256 + 128 + e];
    gr[rt*384 + r] = acc;
}

// Bkq rows 0..127: G = Wq^T Wk;  row 128: wkb = Wk^T bq;  row 129: Ww[0][128:256]
// biaskq: 0..127: Wq^T bk;  128: bq.bk;  129: bw
__global__ void k_bkq(const float* __restrict__ Wq, const float* __restrict__ Wk,
                      const float* __restrict__ bq, const float* __restrict__ bk,
                      const float* __restrict__ Ww, const float* __restrict__ bw,
                      float* __restrict__ Bkq, float* __restrict__ biaskq) {
    int r = blockIdx.x, d = threadIdx.x;
    if (r < 128) {
        float acc = 0.f;
        for (int n = 0; n < 128; ++n) acc += Wq[n*128 + r] * Wk[n*128 + d];
        Bkq[r*128 + d] = acc;
        if (d == 0) {
            float b0 = 0.f;
            for (int n = 0; n < 128; ++n) b0 += Wq[n*128 + r] * bk[n];
            biaskq[r] = b0;
        }
    } else if (r == 128) {
        float acc = 0.f;
        for (int n = 0; n < 128; ++n) acc += bq[n] * Wk[n*128 + d];
        Bkq[128*128 + d] = acc;
        if (d == 0) {
            float c0 = 0.f;
            for (int n = 0; n < 128; ++n) c0 += bq[n] * bk[n];
            biaskq[128] = c0;
        }
    } else {
        Bkq[129*128 + d] = Ww[128 + d];
        if (d == 0) biaskq[129] = bw[0];
    }
}

// ---------------- per-slot GNN question embedding ----------------
// e_q[slot] = mask ? tanh(u @ M^T + bagg) : emb_q[q],  u = emb_q + 0.5*sum(emb_c) + 0.25*sum(m2)
__global__ void k_eq(const float* __restrict__ Mt_g, const float* __restrict__ bagg,
                     const float* __restrict__ emb_q, const float* __restrict__ emb_c,
                     const float* __restrict__ m2, const int* __restrict__ qseq,
                     const int* __restrict__ mseq, const int* __restrict__ qt,
                     float* __restrict__ eq) {
    __shared__ float Mt[128*128];
    __shared__ float ub[2][128];
    int tid = threadIdx.x;
    for (int i = tid; i < 128*128/4; i += 256)
        ((float4*)Mt)[i] = ((const float4*)Mt_g)[i];
    __syncthreads();
    int g = tid >> 7, d = tid & 127;
    for (int it = 0; it < 8; ++it) {
        int slot = blockIdx.x*16 + it*2 + g;            // grid 796 -> slots exactly cover NSz
        int b = slot / Tz, t = slot % Tz;
        int q = qseq[b*Sz + t];
        int msk = mseq[b*Sz + t];
        if (msk) {
            const int* t4 = qt + q*4;
            int c0 = t4[0], c1 = t4[1], c2 = t4[2], c3 = t4[3];
            ub[g][d] = emb_q[q*128 + d]
                     + 0.5f *(emb_c[c0*128+d] + emb_c[c1*128+d] + emb_c[c2*128+d] + emb_c[c3*128+d])
                     + 0.25f*(m2[c0*128+d]  + m2[c1*128+d]  + m2[c2*128+d]  + m2[c3*128+d]);
        }
        __syncthreads();
        if (msk) {
            float acc = bagg[d];
            const float* urow = ub[g];
            for (int e = 0; e < 128; ++e) acc += Mt[e*128 + d] * urow[e];
            eq[slot*128 + d] = tanhf(acc);
        } else {
            eq[slot*128 + d] = emb_q[q*128 + d];
        }
        __syncthreads();
    }
}

// ---------------- generic tiled fp32 GEMM: C[s][n] = A[s][:128] . Bm[n][:128] + epilogue ----
// MODE 0: + bias[n]   (kq path)     MODE 1: + gr[rt(s)][n]  (gi1 path)
template<int MODE>
__global__ void k_gemm(const float* __restrict__ A, const float* __restrict__ Bm,
                       int ldb, int nB, float* __restrict__ C, int ldc,
                       const float* __restrict__ bias, const float* __restrict__ gr,
                       const int* __restrict__ cseq) {
    __shared__ float As[64][33];
    __shared__ float Bs[64][33];
    __shared__ int rtb[64];
    int tx = threadIdx.x, ty = threadIdx.y;
    int tid = ty*16 + tx;
    int m0 = blockIdx.x * 64;
    int n0 = blockIdx.y * 64;
    if (MODE == 1 && tid < 64) {
        int s = m0 + tid;
        int b = s / Tz, t = s % Tz;
        rtb[tid] = cseq[b*Sz + t];
    }
    float acc[4][4];
    #pragma unroll
    for (int i = 0; i < 4; ++i)
        #pragma unroll
        for (int j = 0; j < 4; ++j) acc[i][j] = 0.f;

    for (int kc = 0; kc < 128; kc += 32) {
        #pragma unroll
        for (int l = 0; l < 2; ++l) {
            int v = tid*2 + l;                 // 0..511
            int row = v >> 3, c4 = (v & 7) << 2;
            float4 av = *(const float4*)(A + (size_t)(m0+row)*128 + kc + c4);
            As[row][c4+0] = av.x; As[row][c4+1] = av.y; As[row][c4+2] = av.z; As[row][c4+3] = av.w;
            int nrow = n0 + row;
            float4 bv = make_float4(0.f, 0.f, 0.f, 0.f);
            if (nrow < nB) bv = *(const float4*)(Bm + (size_t)nrow*ldb + kc + c4);
            Bs[row][c4+0] = bv.x; Bs[row][c4+1] = bv.y; Bs[row][c4+2] = bv.z; Bs[row][c4+3] = bv.w;
        }
        __syncthreads();
        #pragma unroll 8
        for (int k = 0; k < 32; ++k) {
            float av[4], bv[4];
            #pragma unroll
            for (int i = 0; i < 4; ++i) av[i] = As[ty*4+i][k];
            #pragma unroll
            for (int j = 0; j < 4; ++j) bv[j] = Bs[tx*4+j][k];
            #pragma unroll
            for (int i = 0; i < 4; ++i)
                #pragma unroll
                for (int j = 0; j < 4; ++j) acc[i][j] += av[i]*bv[j];
        }
        __syncthreads();
    }
    #pragma unroll
    for (int i = 0; i < 4; ++i) {
        int s = m0 + ty*4 + i;
        #pragma unroll
        for (int j = 0; j < 4; ++j) {
            int col = n0 + tx*4 + j;
            if (col < nB) {
                float v = acc[i][j];
                if (MODE == 0) v += bias[col];
                else           v += gr[rtb[ty*4+i]*384 + col];
                C[(size_t)s*ldc + col] = v;
            }
        }
    }
}

// ---------------- sequential GRU scan: register-resident bf16 weights ----------------
__device__ __forceinline__ float bf_lo(unsigned u){ return __uint_as_float(u << 16); }
__device__ __forceinline__ float bf_hi(unsigned u){ return __uint_as_float(u & 0xffff0000u); }
__device__ __forceinline__ unsigned f2bf(float x){          // RNE round to bf16 (bits in low 16)
    unsigned u = __float_as_uint(x);
    return (u + 0x7fffu + ((u >> 16) & 1u)) >> 16;
}
__device__ __forceinline__ unsigned pk2(float a, float b){
    return f2bf(a) | (f2bf(b) << 16);
}
__device__ __forceinline__ float sigm(float x){ return 1.f/(1.f + __expf(-x)); }

// one block per batch row; 384 threads; Whh1/Wih2/Whh2 rows live in VGPRs as bf16 pairs
__global__ void __launch_bounds__(384, 2)
k_scan(const float* __restrict__ gi1,
       const float* __restrict__ Whh1, const float* __restrict__ bhh1,
       const float* __restrict__ Wih2, const float* __restrict__ bih2,
       const float* __restrict__ Whh2, const float* __restrict__ bhh2,
       float* __restrict__ stateh) {
    __shared__ float h1s[128], h2s[128];
    __shared__ float ghA[384], ghC[384], giB[384];
    int b = blockIdx.x, r = threadIdx.x;

    unsigned wA[64], wB[64], wC[64];
    {
        const float4* a4 = (const float4*)(Whh1 + (size_t)r*128);
        const float4* b4 = (const float4*)(Wih2 + (size_t)r*128);
        const float4* c4 = (const float4*)(Whh2 + (size_t)r*128);
        #pragma unroll
        for (int k = 0; k < 32; ++k) {
            float4 av = a4[k]; wA[2*k] = pk2(av.x, av.y); wA[2*k+1] = pk2(av.z, av.w);
            float4 bv = b4[k]; wB[2*k] = pk2(bv.x, bv.y); wB[2*k+1] = pk2(bv.z, bv.w);
            float4 cv = c4[k]; wC[2*k] = pk2(cv.x, cv.y); wC[2*k+1] = pk2(cv.z, cv.w);
        }
    }
    float bA = bhh1[r], bB = bih2[r], bC = bhh2[r];
    if (r < 128) { h1s[r] = 0.f; h2s[r] = 0.f; }
    __syncthreads();

    for (int t = 0; t < Tz; ++t) {
        size_t row = (size_t)(b*Tz + t);
        // prefetch input-gate values for this step (only gate threads need them)
        float g0 = 0.f, g1 = 0.f, g2 = 0.f;
        if (r < 128) {
            const float* gp = gi1 + row*384;
            g0 = gp[r]; g1 = gp[r+128]; g2 = gp[r+256];
        }
        // phase A: ghA = Whh1@h1 + bhh1 ; ghC = Whh2@h2 + bhh2  (h2 pre-update)
        {
            float a0=0.f,a1=0.f,a2=0.f,a3=0.f, c0=0.f,c1=0.f,c2=0.f,c3=0.f;
            #pragma unroll
            for (int k = 0; k < 32; ++k) {
                float4 h4 = ((const float4*)h1s)[k];     // LDS broadcast
                float4 g4 = ((const float4*)h2s)[k];
                unsigned wa0 = wA[2*k], wa1 = wA[2*k+1];
                unsigned wc0 = wC[2*k], wc1 = wC[2*k+1];
                a0 += bf_lo(wa0)*h4.x; a1 += bf_hi(wa0)*h4.y;
                a2 += bf_lo(wa1)*h4.z; a3 += bf_hi(wa1)*h4.w;
                c0 += bf_lo(wc0)*g4.x; c1 += bf_hi(wc0)*g4.y;
                c2 += bf_lo(wc1)*g4.z; c3 += bf_hi(wc1)*g4.w;
            }
            ghA[r] = bA + ((a0+a1)+(a2+a3));
            ghC[r] = bC + ((c0+c1)+(c2+c3));
        }
        __syncthreads();
        if (r < 128) {
            float rr = sigm(g0 + ghA[r]);
            float zz = sigm(g1 + ghA[r+128]);
            float nn = tanhf(g2 + rr*ghA[r+256]);
            h1s[r] = (1.f - zz)*nn + zz*h1s[r];
        }
        __syncthreads();
        // phase B: giB = Wih2@h1' + bih2
        {
            float d0=0.f,d1=0.f,d2=0.f,d3=0.f;
            #pragma unroll
            for (int k = 0; k < 32; ++k) {
                float4 h4 = ((const float4*)h1s)[k];
                unsigned wb0 = wB[2*k], wb1 = wB[2*k+1];
                d0 += bf_lo(wb0)*h4.x; d1 += bf_hi(wb0)*h4.y;
                d2 += bf_lo(wb1)*h4.z; d3 += bf_hi(wb1)*h4.w;
            }
            giB[r] = bB + ((d0+d1)+(d2+d3));
        }
        __syncthreads();
        if (r < 128) {
            float rr = sigm(giB[r] + ghC[r]);
            float zz = sigm(giB[r+128] + ghC[r+128]);
            float nn = tanhf(giB[r+256] + rr*ghC[r+256]);
            float hnew = (1.f - zz)*nn + zz*h2s[r];
            h2s[r] = hnew;
            stateh[row*128 + r] = hnew;
        }
        __syncthreads();
    }
}

// ---------------- attention + top-k + output, one wave per (b,t) ----------------
__global__ void k_attn(const float* __restrict__ kqb, const int* __restrict__ qseq,
                       const int* __restrict__ qt, const float* __restrict__ emb_q,
                       const float* __restrict__ emb_c, const float* __restrict__ Ww,
                       float* __restrict__ out) {
    int t = blockIdx.x, b = blockIdx.y;
    int lane = threadIdx.x;           // block = 64 = 1 wave
    __shared__ float qc[5][128];
    __shared__ float gq[5];
    int qn = qseq[b*Sz + t + 1];
    for (int idx = lane; idx < 5*128; idx += 64) {
        int i = idx >> 7, d = idx & 127;
        const float* src = (i == 0) ? (emb_q + (size_t)qn*128)
                                    : (emb_c + (size_t)qt[qn*4 + (i-1)]*128);
        qc[i][d] = src[d];
    }
    __syncthreads();
    if (lane < 5) {
        float acc = 0.f;
        for (int d = 0; d < 128; ++d) acc += qc[lane][d]*Ww[d];
        gq[lane] = acc;
    }
    __syncthreads();

    const float NEG = -3.402823466e38f;
    float sv[10]; int si[10];
    #pragma unroll
    for (int k = 0; k < 10; ++k) { sv[k] = NEG; si[k] = 0x7FFFFFFF; }

    for (int j = lane; j <= t; j += 64) {
        const float* krow = kqb + (size_t)(b*Tz + j)*132;
        const float4* kr4 = (const float4*)krow;
        float a0=0.f, a1=0.f, a2=0.f, a3=0.f, a4=0.f;
        #pragma unroll 4
        for (int c = 0; c < 32; ++c) {
            float4 kv = kr4[c];
            float4 q0 = ((const float4*)qc[0])[c];
            float4 q1 = ((const float4*)qc[1])[c];
            float4 q2 = ((const float4*)qc[2])[c];
            float4 q3 = ((const float4*)qc[3])[c];
            float4 q4 = ((const float4*)qc[4])[c];
            a0 += q0.x*kv.x + q0.y*kv.y + q0.z*kv.z + q0.w*kv.w;
            a1 += q1.x*kv.x + q1.y*kv.y + q1.z*kv.z + q1.w*kv.w;
            a2 += q2.x*kv.x + q2.y*kv.y + q2.z*kv.z + q2.w*kv.w;
            a3 += q3.x*kv.x + q3.y*kv.y + q3.z*kv.z + q3.w*kv.w;
            a4 += q4.x*kv.x + q4.y*kv.y + q4.z*kv.z + q4.w*kv.w;
        }
        float kbj = krow[128];
        float scs[5] = {a0+kbj, a1+kbj, a2+kbj, a3+kbj, a4+kbj};
        #pragma unroll
        for (int i = 0; i < 5; ++i) {
            float cv = scs[i]; int ci = i*Sz + j;        // flat idx = i*S + j (ref order)
            #pragma unroll
            for (int k = 0; k < 10; ++k) {
                bool bet = (cv > sv[k]) || (cv == sv[k] && ci < si[k]);
                float tvv = sv[k]; int tii = si[k];
                if (bet) { sv[k] = cv; si[k] = ci; cv = tvv; ci = tii; }
            }
        }
    }

    // 10 rounds of global max (desc value, tie -> lower index), matching lax.top_k order
    float vmax = 0.f, myv = 0.f; int myidx = 0x7FFFFFFF;
    #pragma unroll
    for (int rnd = 0; rnd < 10; ++rnd) {
        float v = sv[0]; int idx = si[0];
        #pragma unroll
        for (int off = 32; off >= 1; off >>= 1) {
            float ov = __shfl_xor(v, off);
            int   oi = __shfl_xor(idx, off);
            if (ov > v || (ov == v && oi < idx)) { v = ov; idx = oi; }
        }
        if (rnd == 0) vmax = v;
        if (lane == rnd) { myv = v; myidx = idx; }
        if (si[0] == idx) {   // owner pops its head
            #pragma unroll
            for (int k = 0; k < 9; ++k) { sv[k] = sv[k+1]; si[k] = si[k+1]; }
            sv[9] = NEG; si[9] = 0x7FFFFFFF;
        }
    }

    float num = 0.f, den = 0.f;
    if (lane < 10 && myidx != 0x7FFFFFFF) {
        float a = expf(myv - vmax);
        int ik = myidx / Sz, jk = myidx % Sz;
        float gsj = kqb[(size_t)(b*Tz + jk)*132 + 129];       // Ww-state dot + bw
        float f = 1.f/(1.f + expf(-(gq[ik] + gsj)));
        num = a*f; den = a;
    }
    #pragma unroll
    for (int off = 32; off >= 1; off >>= 1) {
        num += __shfl_xor(num, off);
        den += __shfl_xor(den, off);
    }
    if (lane == 0) out[b*Sz + t + 1] = num/den;
}

// ---------------- host ----------------
static inline size_t alup(size_t x) { return (x + 255) & ~(size_t)255; }

extern "C" void kernel_launch(void* const* d_in, const int* in_sizes, int n_in,
                              void* d_out, int out_size, void* d_ws, size_t ws_size,
                              hipStream_t stream) {
    (void)in_sizes; (void)n_in; (void)ws_size;
    const float* emb_q = (const float*)d_in[0];
    const float* emb_c = (const float*)d_in[1];
    const float* emb_r = (const float*)d_in[2];
    const float* Wih1  = (const float*)d_in[3];
    const float* Whh1  = (const float*)d_in[4];
    const float* bih1  = (const float*)d_in[5];
    const float* bhh1  = (const float*)d_in[6];
    const float* Wih2  = (const float*)d_in[7];
    const float* Whh2  = (const float*)d_in[8];
    const float* bih2  = (const float*)d_in[9];
    const float* bhh2  = (const float*)d_in[10];
    const float* Wg1   = (const float*)d_in[11];
    const float* Wg2   = (const float*)d_in[12];
    const float* Wg3   = (const float*)d_in[13];
    const float* Wagg  = (const float*)d_in[14];
    const float* bagg  = (const float*)d_in[15];
    const float* Wq    = (const float*)d_in[16];
    const float* bq    = (const float*)d_in[17];
    const float* Wk    = (const float*)d_in[18];
    const float* bk    = (const float*)d_in[19];
    const float* Ww    = (const float*)d_in[20];
    const float* bw    = (const float*)d_in[21];
    const int* qseq    = (const int*)d_in[22];
    const int* cseq    = (const int*)d_in[23];
    const int* mseq    = (const int*)d_in[24];
    const int* qtab    = (const int*)d_in[25];
    float* out = (float*)d_out;

    char* p = (char*)d_ws;
    auto alloc = [&](size_t bytes) { char* r = p; p += alup(bytes); return r; };
    int*   cnt    = (int*)  alloc(4096);
    int*   fill   = (int*)  alloc(4096);               // contiguous with cnt
    int*   offs   = (int*)  alloc(1001*4);
    int*   edge_q = (int*)  alloc((size_t)NEz*4);
    float* m2     = (float*)alloc((size_t)NCz*128*4);
    float* T1     = (float*)alloc(128*128*4);
    float* T2     = (float*)alloc(128*128*4);
    float* Mt     = (float*)alloc(128*128*4);
    float* gr     = (float*)alloc(2*384*4);
    float* Bkq    = (float*)alloc(132*128*4);
    float* biaskq = (float*)alloc(132*4);
    float* eq     = (float*)alloc((size_t)NSz*128*4);
    float* gi1    = (float*)alloc((size_t)NSz*384*4);
    float* stateh = (float*)alloc((size_t)NSz*128*4);
    float* kqb    = (float*)alloc((size_t)NSz*132*4);

    hipMemsetAsync(cnt, 0, 8192, stream);                       // cnt + fill
    hipMemsetAsync(d_out, 0, (size_t)out_size*4, stream);       // y[:,0] = 0

    k_count<<<(NEz+255)/256, 256, 0, stream>>>(qtab, cnt);
    k_offs <<<1, 1024, 0, stream>>>(cnt, offs);
    k_fill <<<(NEz+255)/256, 256, 0, stream>>>(qtab, offs, fill, edge_q);
    k_m2   <<<NCz, 512, 0, stream>>>(qtab, offs, edge_q, emb_q, emb_c, m2);

    k_mm128<false><<<128, 128, 0, stream>>>(Wg2, Wg1, T1);      // T1 = Wg2*Wg1
    k_mm128<false><<<128, 128, 0, stream>>>(Wg3, T1, T2);       // T2 = Wg3*T1
    k_mm128<true> <<<128, 128, 0, stream>>>(Wagg, T2, Mt);      // Mt = (Wagg*T2)^T
    k_gr  <<<1, 768, 0, stream>>>(emb_r, Wih1, bih1, gr);
    k_bkq <<<130, 128, 0, stream>>>(Wq, Wk, bq, bk, Ww, bw, Bkq, biaskq);

    k_eq  <<<NSz/16, 256, 0, stream>>>(Mt, bagg, emb_q, emb_c, m2, qseq, mseq, qtab, eq);

    k_gemm<1><<<dim3(NSz/64, 6), dim3(16,16), 0, stream>>>(eq, Wih1, 256, 384,
                                                           gi1, 384, nullptr, gr, cseq);
    k_scan<<<Bz, 384, 0, stream>>>(gi1, Whh1, bhh1, Wih2, bih2, Whh2, bhh2, stateh);
    k_gemm<0><<<dim3(NSz/64, 3), dim3(16,16), 0, stream>>>(stateh, Bkq, 128, 132,
                                                           kqb, 132, biaskq, nullptr, nullptr);
    k_attn<<<dim3(Tz, Bz), 64, 0, stream>>>(kqb, qseq, qtab, emb_q, emb_c, Ww, out);
}

// Round 3
// 829.696 us; speedup vs baseline: 4.6054x; 3.8364x over previous
//
#include <hip/hip_runtime.h>
#include <math.h>

#define Bz 64
#define Sz 200
#define Dz 128
#define NQz 50000
#define NCz 1000
#define MCz 4
#define Kz 10
#define Tz 199            // S-1 scan steps
#define NSz (Bz*Tz)       // 12736 (b,t) slots; 12736/64 = 199 exactly
#define NEz (NQz*MCz)     // 200000 edges

// ---------------- GNN: CSR build + per-concept aggregation ----------------
__global__ void k_count(const int* __restrict__ qt, int* __restrict__ cnt) {
    int e = blockIdx.x*256 + threadIdx.x;
    if (e < NEz) atomicAdd(&cnt[qt[e]], 1);
}

__global__ void k_offs(const int* __restrict__ cnt, int* __restrict__ offs) {
    __shared__ int s[1024];
    int tid = threadIdx.x;
    s[tid] = (tid < NCz) ? cnt[tid] : 0;
    __syncthreads();
    for (int off = 1; off < 1024; off <<= 1) {
        int add = (tid >= off) ? s[tid - off] : 0;
        __syncthreads();
        s[tid] += add;
        __syncthreads();
    }
    if (tid < NCz) offs[tid + 1] = s[tid];
    if (tid == 0) offs[0] = 0;
}

__global__ void k_fill(const int* __restrict__ qt, const int* __restrict__ offs,
                       int* __restrict__ fill, int* __restrict__ edge_q) {
    int e = blockIdx.x*256 + threadIdx.x;
    if (e < NEz) {
        int c = qt[e];
        int pos = atomicAdd(&fill[c], 1);
        edge_q[offs[c] + pos] = e >> 2;     // question id
    }
}

// m2[c] = mean over edges (q->c) of ( emb_q[q] + 0.25*sum_m emb_c[q_table[q][m]] )
__global__ void k_m2(const int* __restrict__ qt, const int* __restrict__ offs,
                     const int* __restrict__ edge_q,
                     const float* __restrict__ emb_q, const float* __restrict__ emb_c,
                     float* __restrict__ m2) {
    int c = blockIdx.x;
    int g = threadIdx.x >> 7;      // 0..3
    int d = threadIdx.x & 127;
    int e0 = offs[c], e1 = offs[c+1];
    float acc = 0.f;
    for (int e = e0 + g; e < e1; e += 4) {
        int q = edge_q[e];
        const int* t4 = qt + q*4;
        int c0 = t4[0], c1 = t4[1], c2 = t4[2], c3 = t4[3];
        acc += emb_q[q*128 + d]
             + 0.25f*(emb_c[c0*128+d] + emb_c[c1*128+d] + emb_c[c2*128+d] + emb_c[c3*128+d]);
    }
    __shared__ float ps[4][128];
    ps[g][d] = acc;
    __syncthreads();
    if (g == 0) {
        float tot = ps[0][d] + ps[1][d] + ps[2][d] + ps[3][d];
        float cn = (float)(e1 - e0);
        m2[c*128 + d] = tot / fmaxf(cn, 1.0f);
    }
}

// ---------------- small 128x128 matmuls (weight folding) ----------------
template<bool TR>
__global__ void k_mm128(const float* __restrict__ X, const float* __restrict__ Y,
                        float* __restrict__ out) {
    int r = blockIdx.x, c = threadIdx.x;
    float acc = 0.f;
    for (int e = 0; e < 128; ++e) acc += X[r*128 + e] * Y[e*128 + c];
    if (TR) out[c*128 + r] = acc;           // store transposed (Mt[d][r] = M[r][d])
    else    out[r*128 + c] = acc;
}

// gr[rt][r] = bih1[r] + sum_e emb_r[rt][e]*Wih1[r][128+e]   (response-part of gi1, bias folded)
__global__ void k_gr(const float* __restrict__ emb_r, const float* __restrict__ Wih1,
                     const float* __restrict__ bih1, float* __restrict__ gr) {
    int rt = threadIdx.x / 384, r = threadIdx.x % 384;   // block 768
    float acc = bih1[r];
    for (int e = 0; e < 128; ++e) acc += emb_r[rt*128 + e] * Wih1[r*256 + 128 + e];
    gr[rt*384 + r] = acc;
}

// Bkq rows 0..127: G = Wq^T Wk;  row 128: wkb = Wk^T bq;  row 129: Ww[0][128:256]
// biaskq: 0..127: Wq^T bk;  128: bq.bk;  129: bw
__global__ void k_bkq(const float* __restrict__ Wq, const float* __restrict__ Wk,
                      const float* __restrict__ bq, const float* __restrict__ bk,
                      const float* __restrict__ Ww, const float* __restrict__ bw,
                      float* __restrict__ Bkq, float* __restrict__ biaskq) {
    int r = blockIdx.x, d = threadIdx.x;
    if (r < 128) {
        float acc = 0.f;
        for (int n = 0; n < 128; ++n) acc += Wq[n*128 + r] * Wk[n*128 + d];
        Bkq[r*128 + d] = acc;
        if (d == 0) {
            float b0 = 0.f;
            for (int n = 0; n < 128; ++n) b0 += Wq[n*128 + r] * bk[n];
            biaskq[r] = b0;
        }
    } else if (r == 128) {
        float acc = 0.f;
        for (int n = 0; n < 128; ++n) acc += bq[n] * Wk[n*128 + d];
        Bkq[128*128 + d] = acc;
        if (d == 0) {
            float c0 = 0.f;
            for (int n = 0; n < 128; ++n) c0 += bq[n] * bk[n];
            biaskq[128] = c0;
        }
    } else {
        Bkq[129*128 + d] = Ww[128 + d];
        if (d == 0) biaskq[129] = bw[0];
    }
}

// ---------------- per-slot GNN question embedding ----------------
// e_q[slot] = mask ? tanh(u @ M^T + bagg) : emb_q[q],  u = emb_q + 0.5*sum(emb_c) + 0.25*sum(m2)
__global__ void k_eq(const float* __restrict__ Mt_g, const float* __restrict__ bagg,
                     const float* __restrict__ emb_q, const float* __restrict__ emb_c,
                     const float* __restrict__ m2, const int* __restrict__ qseq,
                     const int* __restrict__ mseq, const int* __restrict__ qt,
                     float* __restrict__ eq) {
    __shared__ float Mt[128*128];
    __shared__ float ub[2][128];
    int tid = threadIdx.x;
    for (int i = tid; i < 128*128/4; i += 256)
        ((float4*)Mt)[i] = ((const float4*)Mt_g)[i];
    __syncthreads();
    int g = tid >> 7, d = tid & 127;
    for (int it = 0; it < 8; ++it) {
        int slot = blockIdx.x*16 + it*2 + g;            // grid 796 -> slots exactly cover NSz
        int b = slot / Tz, t = slot % Tz;
        int q = qseq[b*Sz + t];
        int msk = mseq[b*Sz + t];
        if (msk) {
            const int* t4 = qt + q*4;
            int c0 = t4[0], c1 = t4[1], c2 = t4[2], c3 = t4[3];
            ub[g][d] = emb_q[q*128 + d]
                     + 0.5f *(emb_c[c0*128+d] + emb_c[c1*128+d] + emb_c[c2*128+d] + emb_c[c3*128+d])
                     + 0.25f*(m2[c0*128+d]  + m2[c1*128+d]  + m2[c2*128+d]  + m2[c3*128+d]);
        }
        __syncthreads();
        if (msk) {
            float acc = bagg[d];
            const float* urow = ub[g];
            for (int e = 0; e < 128; ++e) acc += Mt[e*128 + d] * urow[e];
            eq[slot*128 + d] = tanhf(acc);
        } else {
            eq[slot*128 + d] = emb_q[q*128 + d];
        }
        __syncthreads();
    }
}

// ---------------- generic tiled fp32 GEMM: C[s][n] = A[s][:128] . Bm[n][:128] + epilogue ----
// MODE 0: + bias[n]   (kq path)     MODE 1: + gr[rt(s)][n]  (gi1 path)
template<int MODE>
__global__ void k_gemm(const float* __restrict__ A, const float* __restrict__ Bm,
                       int ldb, int nB, float* __restrict__ C, int ldc,
                       const float* __restrict__ bias, const float* __restrict__ gr,
                       const int* __restrict__ cseq) {
    __shared__ float As[64][33];
    __shared__ float Bs[64][33];
    __shared__ int rtb[64];
    int tx = threadIdx.x, ty = threadIdx.y;
    int tid = ty*16 + tx;
    int m0 = blockIdx.x * 64;
    int n0 = blockIdx.y * 64;
    if (MODE == 1 && tid < 64) {
        int s = m0 + tid;
        int b = s / Tz, t = s % Tz;
        rtb[tid] = cseq[b*Sz + t];
    }
    float acc[4][4];
    #pragma unroll
    for (int i = 0; i < 4; ++i)
        #pragma unroll
        for (int j = 0; j < 4; ++j) acc[i][j] = 0.f;

    for (int kc = 0; kc < 128; kc += 32) {
        #pragma unroll
        for (int l = 0; l < 2; ++l) {
            int v = tid*2 + l;                 // 0..511
            int row = v >> 3, c4 = (v & 7) << 2;
            float4 av = *(const float4*)(A + (size_t)(m0+row)*128 + kc + c4);
            As[row][c4+0] = av.x; As[row][c4+1] = av.y; As[row][c4+2] = av.z; As[row][c4+3] = av.w;
            int nrow = n0 + row;
            float4 bv = make_float4(0.f, 0.f, 0.f, 0.f);
            if (nrow < nB) bv = *(const float4*)(Bm + (size_t)nrow*ldb + kc + c4);
            Bs[row][c4+0] = bv.x; Bs[row][c4+1] = bv.y; Bs[row][c4+2] = bv.z; Bs[row][c4+3] = bv.w;
        }
        __syncthreads();
        #pragma unroll 8
        for (int k = 0; k < 32; ++k) {
            float av[4], bv[4];
            #pragma unroll
            for (int i = 0; i < 4; ++i) av[i] = As[ty*4+i][k];
            #pragma unroll
            for (int j = 0; j < 4; ++j) bv[j] = Bs[tx*4+j][k];
            #pragma unroll
            for (int i = 0; i < 4; ++i)
                #pragma unroll
                for (int j = 0; j < 4; ++j) acc[i][j] += av[i]*bv[j];
        }
        __syncthreads();
    }
    #pragma unroll
    for (int i = 0; i < 4; ++i) {
        int s = m0 + ty*4 + i;
        #pragma unroll
        for (int j = 0; j < 4; ++j) {
            int col = n0 + tx*4 + j;
            if (col < nB) {
                float v = acc[i][j];
                if (MODE == 0) v += bias[col];
                else           v += gr[rtb[ty*4+i]*384 + col];
                C[(size_t)s*ldc + col] = v;
            }
        }
    }
}

// ---------------- sequential GRU scan: register-resident bf16 weights ----------------
__device__ __forceinline__ float bf_lo(unsigned u){ return __uint_as_float(u << 16); }
__device__ __forceinline__ float bf_hi(unsigned u){ return __uint_as_float(u & 0xffff0000u); }
__device__ __forceinline__ unsigned f2bf(float x){          // RNE round to bf16 (bits in low 16)
    unsigned u = __float_as_uint(x);
    return (u + 0x7fffu + ((u >> 16) & 1u)) >> 16;
}
__device__ __forceinline__ unsigned pk2(float a, float b){
    return f2bf(a) | (f2bf(b) << 16);
}
__device__ __forceinline__ float sigm(float x){ return 1.f/(1.f + __expf(-x)); }

#if __has_builtin(__builtin_amdgcn_fdot2_f32_bf16)
#define HAVE_DOT2 1
typedef __attribute__((ext_vector_type(2))) short short2v;
__device__ __forceinline__ float bdot2(unsigned w, unsigned h, float acc) {
    return __builtin_amdgcn_fdot2_f32_bf16(__builtin_bit_cast(short2v, w),
                                           __builtin_bit_cast(short2v, h), acc, false);
}
#else
#define HAVE_DOT2 0
#endif

// one block per batch row; 384 threads; Whh1/Wih2/Whh2 rows live in VGPRs as bf16 pairs.
// __launch_bounds__(384,1): 6-wave block -> 2 waves/SIMD -> 256-VGPR cap (need ~220, no spill).
__global__ void __launch_bounds__(384, 1)
k_scan(const float* __restrict__ gi1,
       const float* __restrict__ Whh1, const float* __restrict__ bhh1,
       const float* __restrict__ Wih2, const float* __restrict__ bih2,
       const float* __restrict__ Whh2, const float* __restrict__ bhh2,
       float* __restrict__ stateh) {
    int b = blockIdx.x, r = threadIdx.x;

    unsigned wA[64], wB[64], wC[64];
    {
        const float4* a4 = (const float4*)(Whh1 + (size_t)r*128);
        const float4* b4 = (const float4*)(Wih2 + (size_t)r*128);
        const float4* c4 = (const float4*)(Whh2 + (size_t)r*128);
        #pragma unroll
        for (int k = 0; k < 32; ++k) {
            float4 av = a4[k]; wA[2*k] = pk2(av.x, av.y); wA[2*k+1] = pk2(av.z, av.w);
            float4 bv = b4[k]; wB[2*k] = pk2(bv.x, bv.y); wB[2*k+1] = pk2(bv.z, bv.w);
            float4 cv = c4[k]; wC[2*k] = pk2(cv.x, cv.y); wC[2*k+1] = pk2(cv.z, cv.w);
        }
    }
    float bA = bhh1[r], bB = bih2[r], bC = bhh2[r];

#if HAVE_DOT2
    // h kept packed bf16 in LDS; gates process 2 units/thread (r<64)
    __shared__ unsigned h1b[64], h2b[64];
    __shared__ float ghA[384], ghC[384], giB[384];
    if (r < 64) { h1b[r] = 0u; h2b[r] = 0u; }
    float g[6];
    #pragma unroll
    for (int i = 0; i < 6; ++i) g[i] = 0.f;
    if (r < 64) {
        const float2* gp = (const float2*)(gi1 + (size_t)(b*Tz)*384);
        float2 x0 = gp[r], x1 = gp[r+64], x2 = gp[r+128];
        g[0]=x0.x; g[1]=x0.y; g[2]=x1.x; g[3]=x1.y; g[4]=x2.x; g[5]=x2.y;
    }
    __syncthreads();
    for (int t = 0; t < Tz; ++t) {
        float n[6];
        #pragma unroll
        for (int i = 0; i < 6; ++i) n[i] = 0.f;
        if (r < 64 && t + 1 < Tz) {                     // prefetch next step's gates
            const float2* gp = (const float2*)(gi1 + (size_t)(b*Tz + t + 1)*384);
            float2 x0 = gp[r], x1 = gp[r+64], x2 = gp[r+128];
            n[0]=x0.x; n[1]=x0.y; n[2]=x1.x; n[3]=x1.y; n[4]=x2.x; n[5]=x2.y;
        }
        // phase A: ghA = Whh1@h1 + bA ; ghC = Whh2@h2 + bC (pre-update h2)
        {
            float a0=0.f,a1=0.f,c0=0.f,c1=0.f;
            #pragma unroll
            for (int k = 0; k < 32; ++k) {
                uint2 hp = ((const uint2*)h1b)[k];       // uniform LDS broadcast
                uint2 qp = ((const uint2*)h2b)[k];
                a0 = bdot2(wA[2*k],   hp.x, a0);
                a1 = bdot2(wA[2*k+1], hp.y, a1);
                c0 = bdot2(wC[2*k],   qp.x, c0);
                c1 = bdot2(wC[2*k+1], qp.y, c1);
            }
            ghA[r] = bA + a0 + a1;
            ghC[r] = bC + c0 + c1;
        }
        __syncthreads();
        if (r < 64) {   // gate 1: update h1 (2 units per thread)
            unsigned hp = h1b[r];
            float ho0 = bf_lo(hp), ho1 = bf_hi(hp);
            float r0 = sigm(g[0] + ghA[2*r]);
            float r1 = sigm(g[1] + ghA[2*r+1]);
            float z0 = sigm(g[2] + ghA[2*r+128]);
            float z1 = sigm(g[3] + ghA[2*r+129]);
            float q0 = tanhf(g[4] + r0*ghA[2*r+256]);
            float q1 = tanhf(g[5] + r1*ghA[2*r+257]);
            float h0 = (1.f - z0)*q0 + z0*ho0;
            float h1v = (1.f - z1)*q1 + z1*ho1;
            h1b[r] = pk2(h0, h1v);
        }
        __syncthreads();
        // phase B: giB = Wih2@h1' + bB
        {
            float d0=0.f,d1=0.f;
            #pragma unroll
            for (int k = 0; k < 32; ++k) {
                uint2 hp = ((const uint2*)h1b)[k];
                d0 = bdot2(wB[2*k],   hp.x, d0);
                d1 = bdot2(wB[2*k+1], hp.y, d1);
            }
            giB[r] = bB + d0 + d1;
        }
        __syncthreads();
        if (r < 64) {   // gate 2: update h2, store fp32 state
            unsigned hp = h2b[r];
            float ho0 = bf_lo(hp), ho1 = bf_hi(hp);
            float r0 = sigm(giB[2*r]     + ghC[2*r]);
            float r1 = sigm(giB[2*r+1]   + ghC[2*r+1]);
            float z0 = sigm(giB[2*r+128] + ghC[2*r+128]);
            float z1 = sigm(giB[2*r+129] + ghC[2*r+129]);
            float q0 = tanhf(giB[2*r+256] + r0*ghC[2*r+256]);
            float q1 = tanhf(giB[2*r+257] + r1*ghC[2*r+257]);
            float h0 = (1.f - z0)*q0 + z0*ho0;
            float h1v = (1.f - z1)*q1 + z1*ho1;
            h2b[r] = pk2(h0, h1v);
            ((float2*)(stateh + (size_t)(b*Tz + t)*128))[r] = make_float2(h0, h1v);
        }
        #pragma unroll
        for (int i = 0; i < 6; ++i) g[i] = n[i];
        __syncthreads();
    }
#else
    // fallback: fp32 h in LDS, unpack-FMA dots (verified round-2 structure)
    __shared__ float h1s[128], h2s[128];
    __shared__ float ghA[384], ghC[384], giB[384];
    if (r < 128) { h1s[r] = 0.f; h2s[r] = 0.f; }
    __syncthreads();
    for (int t = 0; t < Tz; ++t) {
        size_t row = (size_t)(b*Tz + t);
        float g0 = 0.f, g1 = 0.f, g2 = 0.f;
        if (r < 128) {
            const float* gp = gi1 + row*384;
            g0 = gp[r]; g1 = gp[r+128]; g2 = gp[r+256];
        }
        {
            float a0=0.f,a1=0.f,a2=0.f,a3=0.f, c0=0.f,c1=0.f,c2=0.f,c3=0.f;
            #pragma unroll
            for (int k = 0; k < 32; ++k) {
                float4 h4 = ((const float4*)h1s)[k];
                float4 g4 = ((const float4*)h2s)[k];
                unsigned wa0 = wA[2*k], wa1 = wA[2*k+1];
                unsigned wc0 = wC[2*k], wc1 = wC[2*k+1];
                a0 += bf_lo(wa0)*h4.x; a1 += bf_hi(wa0)*h4.y;
                a2 += bf_lo(wa1)*h4.z; a3 += bf_hi(wa1)*h4.w;
                c0 += bf_lo(wc0)*g4.x; c1 += bf_hi(wc0)*g4.y;
                c2 += bf_lo(wc1)*g4.z; c3 += bf_hi(wc1)*g4.w;
            }
            ghA[r] = bA + ((a0+a1)+(a2+a3));
            ghC[r] = bC + ((c0+c1)+(c2+c3));
        }
        __syncthreads();
        if (r < 128) {
            float rr = sigm(g0 + ghA[r]);
            float zz = sigm(g1 + ghA[r+128]);
            float nn = tanhf(g2 + rr*ghA[r+256]);
            h1s[r] = (1.f - zz)*nn + zz*h1s[r];
        }
        __syncthreads();
        {
            float d0=0.f,d1=0.f,d2=0.f,d3=0.f;
            #pragma unroll
            for (int k = 0; k < 32; ++k) {
                float4 h4 = ((const float4*)h1s)[k];
                unsigned wb0 = wB[2*k], wb1 = wB[2*k+1];
                d0 += bf_lo(wb0)*h4.x; d1 += bf_hi(wb0)*h4.y;
                d2 += bf_lo(wb1)*h4.z; d3 += bf_hi(wb1)*h4.w;
            }
            giB[r] = bB + ((d0+d1)+(d2+d3));
        }
        __syncthreads();
        if (r < 128) {
            float rr = sigm(giB[r] + ghC[r]);
            float zz = sigm(giB[r+128] + ghC[r+128]);
            float nn = tanhf(giB[r+256] + rr*ghC[r+256]);
            float hnew = (1.f - zz)*nn + zz*h2s[r];
            h2s[r] = hnew;
            stateh[row*128 + r] = hnew;
        }
        __syncthreads();
    }
#endif
}

// ---------------- attention + top-k + output, one wave per (b,t) ----------------
__global__ void k_attn(const float* __restrict__ kqb, const int* __restrict__ qseq,
                       const int* __restrict__ qt, const float* __restrict__ emb_q,
                       const float* __restrict__ emb_c, const float* __restrict__ Ww,
                       float* __restrict__ out) {
    int t = blockIdx.x, b = blockIdx.y;
    int lane = threadIdx.x;           // block = 64 = 1 wave
    __shared__ float qc[5][128];
    __shared__ float gq[5];
    int qn = qseq[b*Sz + t + 1];
    for (int idx = lane; idx < 5*128; idx += 64) {
        int i = idx >> 7, d = idx & 127;
        const float* src = (i == 0) ? (emb_q + (size_t)qn*128)
                                    : (emb_c + (size_t)qt[qn*4 + (i-1)]*128);
        qc[i][d] = src[d];
    }
    __syncthreads();
    if (lane < 5) {
        float acc = 0.f;
        for (int d = 0; d < 128; ++d) acc += qc[lane][d]*Ww[d];
        gq[lane] = acc;
    }
    __syncthreads();

    const float NEG = -3.402823466e38f;
    float sv[10]; int si[10];
    #pragma unroll
    for (int k = 0; k < 10; ++k) { sv[k] = NEG; si[k] = 0x7FFFFFFF; }

    for (int j = lane; j <= t; j += 64) {
        const float* krow = kqb + (size_t)(b*Tz + j)*132;
        const float4* kr4 = (const float4*)krow;
        float a0=0.f, a1=0.f, a2=0.f, a3=0.f, a4=0.f;
        #pragma unroll 4
        for (int c = 0; c < 32; ++c) {
            float4 kv = kr4[c];
            float4 q0 = ((const float4*)qc[0])[c];
            float4 q1 = ((const float4*)qc[1])[c];
            float4 q2 = ((const float4*)qc[2])[c];
            float4 q3 = ((const float4*)qc[3])[c];
            float4 q4 = ((const float4*)qc[4])[c];
            a0 += q0.x*kv.x + q0.y*kv.y + q0.z*kv.z + q0.w*kv.w;
            a1 += q1.x*kv.x + q1.y*kv.y + q1.z*kv.z + q1.w*kv.w;
            a2 += q2.x*kv.x + q2.y*kv.y + q2.z*kv.z + q2.w*kv.w;
            a3 += q3.x*kv.x + q3.y*kv.y + q3.z*kv.z + q3.w*kv.w;
            a4 += q4.x*kv.x + q4.y*kv.y + q4.z*kv.z + q4.w*kv.w;
        }
        float kbj = krow[128];
        float scs[5] = {a0+kbj, a1+kbj, a2+kbj, a3+kbj, a4+kbj};
        #pragma unroll
        for (int i = 0; i < 5; ++i) {
            float cv = scs[i]; int ci = i*Sz + j;        // flat idx = i*S + j (ref order)
            #pragma unroll
            for (int k = 0; k < 10; ++k) {
                bool bet = (cv > sv[k]) || (cv == sv[k] && ci < si[k]);
                float tvv = sv[k]; int tii = si[k];
                if (bet) { sv[k] = cv; si[k] = ci; cv = tvv; ci = tii; }
            }
        }
    }

    // 10 rounds of global max (desc value, tie -> lower index), matching lax.top_k order
    float vmax = 0.f, myv = 0.f; int myidx = 0x7FFFFFFF;
    #pragma unroll
    for (int rnd = 0; rnd < 10; ++rnd) {
        float v = sv[0]; int idx = si[0];
        #pragma unroll
        for (int off = 32; off >= 1; off >>= 1) {
            float ov = __shfl_xor(v, off);
            int   oi = __shfl_xor(idx, off);
            if (ov > v || (ov == v && oi < idx)) { v = ov; idx = oi; }
        }
        if (rnd == 0) vmax = v;
        if (lane == rnd) { myv = v; myidx = idx; }
        if (si[0] == idx) {   // owner pops its head
            #pragma unroll
            for (int k = 0; k < 9; ++k) { sv[k] = sv[k+1]; si[k] = si[k+1]; }
            sv[9] = NEG; si[9] = 0x7FFFFFFF;
        }
    }

    float num = 0.f, den = 0.f;
    if (lane < 10 && myidx != 0x7FFFFFFF) {
        float a = expf(myv - vmax);
        int ik = myidx / Sz, jk = myidx % Sz;
        float gsj = kqb[(size_t)(b*Tz + jk)*132 + 129];       // Ww-state dot + bw
        float f = 1.f/(1.f + expf(-(gq[ik] + gsj)));
        num = a*f; den = a;
    }
    #pragma unroll
    for (int off = 32; off >= 1; off >>= 1) {
        num += __shfl_xor(num, off);
        den += __shfl_xor(den, off);
    }
    if (lane == 0) out[b*Sz + t + 1] = num/den;
}

// ---------------- host ----------------
static inline size_t alup(size_t x) { return (x + 255) & ~(size_t)255; }

extern "C" void kernel_launch(void* const* d_in, const int* in_sizes, int n_in,
                              void* d_out, int out_size, void* d_ws, size_t ws_size,
                              hipStream_t stream) {
    (void)in_sizes; (void)n_in; (void)ws_size;
    const float* emb_q = (const float*)d_in[0];
    const float* emb_c = (const float*)d_in[1];
    const float* emb_r = (const float*)d_in[2];
    const float* Wih1  = (const float*)d_in[3];
    const float* Whh1  = (const float*)d_in[4];
    const float* bih1  = (const float*)d_in[5];
    const float* bhh1  = (const float*)d_in[6];
    const float* Wih2  = (const float*)d_in[7];
    const float* Whh2  = (const float*)d_in[8];
    const float* bih2  = (const float*)d_in[9];
    const float* bhh2  = (const float*)d_in[10];
    const float* Wg1   = (const float*)d_in[11];
    const float* Wg2   = (const float*)d_in[12];
    const float* Wg3   = (const float*)d_in[13];
    const float* Wagg  = (const float*)d_in[14];
    const float* bagg  = (const float*)d_in[15];
    const float* Wq    = (const float*)d_in[16];
    const float* bq    = (const float*)d_in[17];
    const float* Wk    = (const float*)d_in[18];
    const float* bk    = (const float*)d_in[19];
    const float* Ww    = (const float*)d_in[20];
    const float* bw    = (const float*)d_in[21];
    const int* qseq    = (const int*)d_in[22];
    const int* cseq    = (const int*)d_in[23];
    const int* mseq    = (const int*)d_in[24];
    const int* qtab    = (const int*)d_in[25];
    float* out = (float*)d_out;

    char* p = (char*)d_ws;
    auto alloc = [&](size_t bytes) { char* r = p; p += alup(bytes); return r; };
    int*   cnt    = (int*)  alloc(4096);
    int*   fill   = (int*)  alloc(4096);               // contiguous with cnt
    int*   offs   = (int*)  alloc(1001*4);
    int*   edge_q = (int*)  alloc((size_t)NEz*4);
    float* m2     = (float*)alloc((size_t)NCz*128*4);
    float* T1     = (float*)alloc(128*128*4);
    float* T2     = (float*)alloc(128*128*4);
    float* Mt     = (float*)alloc(128*128*4);
    float* gr     = (float*)alloc(2*384*4);
    float* Bkq    = (float*)alloc(132*128*4);
    float* biaskq = (float*)alloc(132*4);
    float* eq     = (float*)alloc((size_t)NSz*128*4);
    float* gi1    = (float*)alloc((size_t)NSz*384*4);
    float* stateh = (float*)alloc((size_t)NSz*128*4);
    float* kqb    = (float*)alloc((size_t)NSz*132*4);

    hipMemsetAsync(cnt, 0, 8192, stream);                       // cnt + fill
    hipMemsetAsync(d_out, 0, (size_t)out_size*4, stream);       // y[:,0] = 0

    k_count<<<(NEz+255)/256, 256, 0, stream>>>(qtab, cnt);
    k_offs <<<1, 1024, 0, stream>>>(cnt, offs);
    k_fill <<<(NEz+255)/256, 256, 0, stream>>>(qtab, offs, fill, edge_q);
    k_m2   <<<NCz, 512, 0, stream>>>(qtab, offs, edge_q, emb_q, emb_c, m2);

    k_mm128<false><<<128, 128, 0, stream>>>(Wg2, Wg1, T1);      // T1 = Wg2*Wg1
    k_mm128<false><<<128, 128, 0, stream>>>(Wg3, T1, T2);       // T2 = Wg3*T1
    k_mm128<true> <<<128, 128, 0, stream>>>(Wagg, T2, Mt);      // Mt = (Wagg*T2)^T
    k_gr  <<<1, 768, 0, stream>>>(emb_r, Wih1, bih1, gr);
    k_bkq <<<130, 128, 0, stream>>>(Wq, Wk, bq, bk, Ww, bw, Bkq, biaskq);

    k_eq  <<<NSz/16, 256, 0, stream>>>(Mt, bagg, emb_q, emb_c, m2, qseq, mseq, qtab, eq);

    k_gemm<1><<<dim3(NSz/64, 6), dim3(16,16), 0, stream>>>(eq, Wih1, 256, 384,
                                                           gi1, 384, nullptr, gr, cseq);
    k_scan<<<Bz, 384, 0, stream>>>(gi1, Whh1, bhh1, Wih2, bih2, Whh2, bhh2, stateh);
    k_gemm<0><<<dim3(NSz/64, 3), dim3(16,16), 0, stream>>>(stateh, Bkq, 128, 132,
                                                           kqb, 132, biaskq, nullptr, nullptr);
    k_attn<<<dim3(Tz, Bz), 64, 0, stream>>>(kqb, qseq, qtab, emb_q, emb_c, Ww, out);
}